// Round 12
// baseline (19.647 us; speedup 1.0000x reference)
//
#include <hip/hip_runtime.h>
#include <math.h>

#define D 128
// level 0: R=24 rows/graph (nodes); level 1: R=40 (line graph)
// out (floats): s_h@0, s_t@32768, s_h_line@65536, s_t_line@98304

typedef float f32x4 __attribute__((ext_vector_type(4)));
typedef _Float16 f16x8 __attribute__((ext_vector_type(8)));
typedef __fp16 pk16x2 __attribute__((ext_vector_type(2)));   // cvt_pkrtz return type

union PK4 { pk16x2 p[2]; ushort4 v; };

__device__ __forceinline__ f16x8 cvt8(float4 a, float4 b) {
    union { pk16x2 p[4]; f16x8 v; } u;
    u.p[0] = __builtin_amdgcn_cvt_pkrtz(a.x, a.y);
    u.p[1] = __builtin_amdgcn_cvt_pkrtz(a.z, a.w);
    u.p[2] = __builtin_amdgcn_cvt_pkrtz(b.x, b.y);
    u.p[3] = __builtin_amdgcn_cvt_pkrtz(b.z, b.w);
    return u.v;
}

__device__ __forceinline__ float tanh_fast(float x) {
    float cx = fminf(fmaxf(x, -15.f), 15.f);
    float t = __expf(2.f * cx);
    return __fdividef(t - 1.f, t + 1.f);
}

// MFMA rule (validated r1-r11): mfma(P,Q): lane(lm,lq) reg r = dot(P_row[lq*4+r], Q_row[lm]);
// fragments loaded with row = lane&15, k = (lane>>4)*8 + e.
// LDS swizzle (validated r4-r11): half-index k stored at k ^ ((row&7)<<3) in 128-wide rows.
template <int LEVEL>
__device__ __forceinline__ void body(
    int g, const float* __restrict__ xh, const float* __restrict__ xt,
    const float* __restrict__ WH, const float* __restrict__ WT,
    const float* __restrict__ bH, const float* __restrict__ bT,
    float* __restrict__ osh, float* __restrict__ ost,
    _Float16* GH, _Float16* GT, _Float16* XH, _Float16* XT,
    float* colpart, float* bh_s, float* pt_s, float* ph_s)
{
    constexpr int R = LEVEL ? 40 : 24;
    constexpr int TM = LEVEL ? 3 : 2;
    constexpr int PAD = TM * 16;
    constexpr int ITERS = (2 * PAD * 32) / 256;   // 8 (lvl0) or 12 (lvl1)
    constexpr float invR = 1.f / (float)R;

    const int tid = threadIdx.x;
    const int w = tid >> 6, l = tid & 63;
    const int lm = l & 15, lq = l >> 4;
    const int base = g * R;
    const int tile0 = 2 * w;      // wave owns W row-tiles {tile0,tile0+1} of WH and WT

    // ---- G pad rows zero (dependency-free LDS writes, issued first) ----
    {
        constexpr int GZ = 2 * (PAD - R) * 64;       // ushort4 units
        for (int u = tid; u < GZ; u += 256) {
            const int arr = (u >= (PAD - R) * 64);
            const int rem = arr ? (u - (PAD - R) * 64) : u;
            const int r = R + (rem >> 6), c4 = rem & 63;
            _Float16* Gs = arr ? GT : GH;
            *reinterpret_cast<ushort4*>(&Gs[r * 256 + c4 * 4]) = make_ushort4(0, 0, 0, 0);
        }
    }

    // ---- issue ALL X stage loads up front (single latency exposure) ----
    float4 xv[ITERS];
#pragma unroll
    for (int it = 0; it < ITERS; ++it) {
        const int u = tid + it * 256;
        const int arr = (u >= PAD * 32);
        const int rem = arr ? (u - PAD * 32) : u;
        const int r = rem >> 5, c4 = rem & 31;
        if (r < R) {
            const float* xs = arr ? xt : xh;
            xv[it] = *reinterpret_cast<const float4*>(&xs[(base + r) * D + c4 * 4]);
        } else {
            xv[it] = (float4){0.f, 0.f, 0.f, 0.f};
        }
    }

    // ---- W fragments (loads overlap X latency), packed cvt ----
    f16x8 wf[4][4];               // [0,1]=WH tiles, [2,3]=WT tiles; x [ks]
#pragma unroll
    for (int ks = 0; ks < 4; ++ks) {
        const int k0 = ks * 32 + lq * 8;
#pragma unroll
        for (int t = 0; t < 2; ++t) {
            const float* p1 = WH + ((tile0 + t) * 16 + lm) * D + k0;
            wf[t][ks] = cvt8(*reinterpret_cast<const float4*>(p1),
                             *reinterpret_cast<const float4*>(p1 + 4));
            const float* p2 = WT + ((tile0 + t) * 16 + lm) * D + k0;
            wf[2 + t][ks] = cvt8(*reinterpret_cast<const float4*>(p2),
                                 *reinterpret_cast<const float4*>(p2 + 4));
        }
    }

    // ---- convert + write staged X (loads already in flight/arrived) ----
#pragma unroll
    for (int it = 0; it < ITERS; ++it) {
        const int u = tid + it * 256;
        const int arr = (u >= PAD * 32);
        const int rem = arr ? (u - PAD * 32) : u;
        const int r = rem >> 5, c4 = rem & 31;
        _Float16* Xs = arr ? XT : XH;
        PK4 pk;
        pk.p[0] = __builtin_amdgcn_cvt_pkrtz(xv[it].x, xv[it].y);
        pk.p[1] = __builtin_amdgcn_cvt_pkrtz(xv[it].z, xv[it].w);
        *reinterpret_cast<ushort4*>(&Xs[r * 128 + ((c4 * 4) ^ ((r & 7) << 3))]) = pk.v;
    }
    __syncthreads();

    // ---- G_s = x_s @ [WA|WB]^T + [bA|bB]; wave owns 4 col-tiles; fp16 -> LDS ----
#pragma unroll
    for (int side = 0; side < 2; ++side) {
        const _Float16* Xs = side ? XT : XH;
        const float* __restrict__ bA = side ? bT : bH;
        const float* __restrict__ bB = side ? bH : bT;
        _Float16* Gs = side ? GT : GH;

        f32x4 acc[TM][4];
#pragma unroll
        for (int ti = 0; ti < TM; ++ti)
#pragma unroll
            for (int c2 = 0; c2 < 4; ++c2) acc[ti][c2] = (f32x4){0.f, 0.f, 0.f, 0.f};

#pragma unroll
        for (int ks = 0; ks < 4; ++ks) {
            const int k0 = ks * 32 + lq * 8;
            const int kx = k0 ^ ((lm & 7) << 3);     // row = ti*16+lm -> row&7 == lm&7
            f16x8 q[TM];
#pragma unroll
            for (int ti = 0; ti < TM; ++ti)
                q[ti] = *reinterpret_cast<const f16x8*>(&Xs[(ti * 16 + lm) * 128 + kx]);
#pragma unroll
            for (int c2 = 0; c2 < 4; ++c2) {
                const int wfidx = side ? (c2 ^ 2) : c2;
#pragma unroll
                for (int ti = 0; ti < TM; ++ti)
                    acc[ti][c2] = __builtin_amdgcn_mfma_f32_16x16x32_f16(
                        wf[wfidx][ks], q[ti], acc[ti][c2], 0, 0, 0);
            }
        }

        // epilogue: lane holds G[i=ti*16+lm][n=ctl*16+lq*4+r]
#pragma unroll
        for (int c2 = 0; c2 < 4; ++c2) {
            const int ctl = (c2 < 2) ? (tile0 + c2) : (8 + tile0 + (c2 - 2));
            const int nc = ctl * 16 + lq * 4;
            const float* bp = (ctl < 8) ? (bA + nc) : (bB + nc - 128);
            float4 b4 = *reinterpret_cast<const float4*>(bp);
#pragma unroll
            for (int ti = 0; ti < TM; ++ti) {
                int i = ti * 16 + lm;
                if (i < R) {
                    PK4 pk;
                    pk.p[0] = __builtin_amdgcn_cvt_pkrtz(acc[ti][c2][0] + b4.x,
                                                         acc[ti][c2][1] + b4.y);
                    pk.p[1] = __builtin_amdgcn_cvt_pkrtz(acc[ti][c2][2] + b4.z,
                                                         acc[ti][c2][3] + b4.w);
                    *reinterpret_cast<ushort4*>(&Gs[i * 256 + (nc ^ ((i & 7) << 3))]) = pk.v;
                }
            }
        }
    }
    __syncthreads();

    // ---- alpha = tanh(G_h @ G_t^T); wave w<TM owns i-tile w; no clamps (zero pad) ----
    float cs[3] = {0.f, 0.f, 0.f};
    if (w < TM) {
        f32x4 acc2[TM];
#pragma unroll
        for (int tj = 0; tj < TM; ++tj) acc2[tj] = (f32x4){0.f, 0.f, 0.f, 0.f};

        const int ri = w * 16 + lm;
#pragma unroll
        for (int ksa = 0; ksa < 8; ++ksa) {
            const int k0 = ksa * 32 + lq * 8;
            const int kx = k0 ^ ((lm & 7) << 3);
            f16x8 A = *reinterpret_cast<const f16x8*>(&GH[ri * 256 + kx]);
#pragma unroll
            for (int tj = 0; tj < TM; ++tj) {
                f16x8 B = *reinterpret_cast<const f16x8*>(&GT[(tj * 16 + lm) * 256 + kx]);
                acc2[tj] = __builtin_amdgcn_mfma_f32_16x16x32_f16(A, B, acc2[tj], 0, 0, 0);
            }
        }

        float at[TM][4];
#pragma unroll
        for (int tj = 0; tj < TM; ++tj)
#pragma unroll
            for (int r = 0; r < 4; ++r) at[tj][r] = tanh_fast(acc2[tj][r]);

        // row sums over j -> bh_s[i]
#pragma unroll
        for (int r = 0; r < 4; ++r) {
            float s = 0.f;
#pragma unroll
            for (int tj = 0; tj < TM; ++tj) s += at[tj][r];
            s += __shfl_xor(s, 1, 64);
            s += __shfl_xor(s, 2, 64);
            s += __shfl_xor(s, 4, 64);
            s += __shfl_xor(s, 8, 64);
            if (lm == 0) bh_s[w * 16 + lq * 4 + r] = s;
        }
        // col partial sums over this i-tile
#pragma unroll
        for (int tj = 0; tj < TM; ++tj) {
            float s = 0.f;
#pragma unroll
            for (int r = 0; r < 4; ++r) s += at[tj][r];
            s += __shfl_xor(s, 16, 64);
            s += __shfl_xor(s, 32, 64);
            cs[tj] = s;
        }
    }
#pragma unroll
    for (int tj = 0; tj < 3; ++tj)
        if (lq == 0) colpart[w * 48 + tj * 16 + lm] = (tj < TM) ? cs[tj] : 0.f;
    __syncthreads();

    // ---- softmaxes (waves 0,1) OVERLAPPED with output-column preload (all threads) ----
    if (w == 0) {
        float v = (l < 48) ? (colpart[l] + colpart[48 + l] + colpart[96 + l] + colpart[144 + l]) : 0.f;
        float val = (l < R) ? v * invR : -INFINITY;
        float m = val;
        for (int o = 32; o; o >>= 1) m = fmaxf(m, __shfl_xor(m, o, 64));
        float e = (l < R) ? __expf(val - m) : 0.f;
        float s = e;
        for (int o = 32; o; o >>= 1) s += __shfl_xor(s, o, 64);
        if (l < R) pt_s[l] = __fdividef(e, s);
    } else if (w == 1) {
        float val = (l < R) ? bh_s[l] * invR : -INFINITY;
        float m = val;
        for (int o = 32; o; o >>= 1) m = fmaxf(m, __shfl_xor(m, o, 64));
        float e = (l < R) ? __expf(val - m) : 0.f;
        float s = e;
        for (int o = 32; o; o >>= 1) s += __shfl_xor(s, o, 64);
        if (l < R) ph_s[l] = __fdividef(e, s);
    }

    // preload this thread's x column into registers (overlaps softmax above;
    // XT/XH have been stable since barrier #1)
    const int c = tid & 127;
    const _Float16* Xsrc = (tid < 128) ? XT : XH;
    float xcol[R];
#pragma unroll
    for (int j = 0; j < R; ++j)
        xcol[j] = (float)Xsrc[j * 128 + (c ^ ((j & 7) << 3))];
    __syncthreads();

    // ---- output: p (float4 broadcast reads) dot xcol ----
    const float* ps = (tid < 128) ? pt_s : ph_s;
    float a = 0.f;
#pragma unroll
    for (int j4 = 0; j4 < R / 4; ++j4) {
        float4 p4 = *reinterpret_cast<const float4*>(&ps[j4 * 4]);
        a = fmaf(p4.x, xcol[j4 * 4 + 0], a);
        a = fmaf(p4.y, xcol[j4 * 4 + 1], a);
        a = fmaf(p4.z, xcol[j4 * 4 + 2], a);
        a = fmaf(p4.w, xcol[j4 * 4 + 3], a);
    }
    ((tid < 128) ? ost : osh)[g * D + c] = a;
}

__global__ __launch_bounds__(256, 2) void fused_kernel(
    const float* __restrict__ xnh, const float* __restrict__ xnt,
    const float* __restrict__ xlh, const float* __restrict__ xlt,
    const float* __restrict__ Wh, const float* __restrict__ bh,
    const float* __restrict__ Wt, const float* __restrict__ bt,
    const float* __restrict__ Whl, const float* __restrict__ bhl,
    const float* __restrict__ Wtl, const float* __restrict__ btl,
    float* __restrict__ out)
{
    __shared__ __align__(16) _Float16 GH[48 * 256];
    __shared__ __align__(16) _Float16 GT[48 * 256];
    __shared__ __align__(16) _Float16 XH[48 * 128];
    __shared__ __align__(16) _Float16 XT[48 * 128];
    __shared__ __align__(16) float colpart[192];
    __shared__ __align__(16) float bh_s[48];
    __shared__ __align__(16) float pt_s[48];
    __shared__ __align__(16) float ph_s[48];

    int idx = blockIdx.x;
    if (idx < 256)
        body<0>(idx, xnh, xnt, Wh, Wt, bh, bt, out + 0, out + 32768,
                GH, GT, XH, XT, colpart, bh_s, pt_s, ph_s);
    else
        body<1>(idx - 256, xlh, xlt, Whl, Wtl, bhl, btl, out + 65536, out + 98304,
                GH, GT, XH, XT, colpart, bh_s, pt_s, ph_s);
}

extern "C" void kernel_launch(void* const* d_in, const int* in_sizes, int n_in,
                              void* d_out, int out_size, void* d_ws, size_t ws_size,
                              hipStream_t stream) {
    const float* xnh   = (const float*)d_in[0];
    const float* xnt   = (const float*)d_in[1];
    const float* xlh   = (const float*)d_in[2];
    const float* xlt   = (const float*)d_in[3];
    const float* Wh_w  = (const float*)d_in[4];
    const float* Wh_b  = (const float*)d_in[5];
    const float* Wt_w  = (const float*)d_in[6];
    const float* Wt_b  = (const float*)d_in[7];
    const float* Whl_w = (const float*)d_in[8];
    const float* Whl_b = (const float*)d_in[9];
    const float* Wtl_w = (const float*)d_in[10];
    const float* Wtl_b = (const float*)d_in[11];

    float* out = (float*)d_out;

    fused_kernel<<<512, 256, 0, stream>>>(xnh, xnt, xlh, xlt,
                                          Wh_w, Wh_b, Wt_w, Wt_b,
                                          Whl_w, Whl_b, Wtl_w, Wtl_b, out);
}

// Round 13
// 18.429 us; speedup vs baseline: 1.0661x; 1.0661x over previous
//
#include <hip/hip_runtime.h>
#include <math.h>

#define D 128
// level 0: R=24 rows/graph (nodes); level 1: R=40 (line graph)
// out (floats): s_h@0, s_t@32768, s_h_line@65536, s_t_line@98304

typedef float f32x4 __attribute__((ext_vector_type(4)));
typedef _Float16 f16x8 __attribute__((ext_vector_type(8)));
typedef __fp16 pk16x2 __attribute__((ext_vector_type(2)));   // cvt_pkrtz return type

union PK4 { pk16x2 p[2]; ushort4 v; };

__device__ __forceinline__ f16x8 cvt8(float4 a, float4 b) {
    union { pk16x2 p[4]; f16x8 v; } u;
    u.p[0] = __builtin_amdgcn_cvt_pkrtz(a.x, a.y);
    u.p[1] = __builtin_amdgcn_cvt_pkrtz(a.z, a.w);
    u.p[2] = __builtin_amdgcn_cvt_pkrtz(b.x, b.y);
    u.p[3] = __builtin_amdgcn_cvt_pkrtz(b.z, b.w);
    return u.v;
}

__device__ __forceinline__ float tanh_fast(float x) {
    float cx = fminf(fmaxf(x, -15.f), 15.f);
    float t = __expf(2.f * cx);
    return __fdividef(t - 1.f, t + 1.f);
}

// MFMA rule (validated r1-r12): mfma(P,Q): lane(lm,lq) reg r = dot(P_row[lq*4+r], Q_row[lm]);
// fragments loaded with row = lane&15, k = (lane>>4)*8 + e.
// LDS swizzle (validated r4-r12): half-index k stored at k ^ ((row&7)<<3) in 128-wide rows.
// 512 threads = 8 waves: wave w owns W row-tile w of WH and of WT (G col-tiles {w, 8+w}).
template <int LEVEL>
__device__ __forceinline__ void body(
    int g, const float* __restrict__ xh, const float* __restrict__ xt,
    const float* __restrict__ WH, const float* __restrict__ WT,
    const float* __restrict__ bH, const float* __restrict__ bT,
    float* __restrict__ osh, float* __restrict__ ost,
    _Float16* GH, _Float16* GT, _Float16* XH, _Float16* XT,
    float* colpart, float* bh_s, float* pt_s, float* ph_s)
{
    constexpr int R = LEVEL ? 40 : 24;
    constexpr int TM = LEVEL ? 3 : 2;
    constexpr int PAD = TM * 16;
    constexpr int ITERS = (2 * PAD * 32) / 512;   // 4 (lvl0) or 6 (lvl1)
    constexpr float invR = 1.f / (float)R;

    const int tid = threadIdx.x;
    const int w = tid >> 6, l = tid & 63;
    const int lm = l & 15, lq = l >> 4;
    const int base = g * R;

    // ---- G pad rows zero (dependency-free LDS writes, issued first) ----
    {
        constexpr int GZ = 2 * (PAD - R) * 64;       // ushort4 units
        for (int u = tid; u < GZ; u += 512) {
            const int arr = (u >= (PAD - R) * 64);
            const int rem = arr ? (u - (PAD - R) * 64) : u;
            const int r = R + (rem >> 6), c4 = rem & 63;
            _Float16* Gs = arr ? GT : GH;
            *reinterpret_cast<ushort4*>(&Gs[r * 256 + c4 * 4]) = make_ushort4(0, 0, 0, 0);
        }
    }

    // ---- issue ALL X stage loads up front (single latency exposure) ----
    float4 xv[ITERS];
#pragma unroll
    for (int it = 0; it < ITERS; ++it) {
        const int u = tid + it * 512;
        const int arr = (u >= PAD * 32);
        const int rem = arr ? (u - PAD * 32) : u;
        const int r = rem >> 5, c4 = rem & 31;
        if (r < R) {
            const float* xs = arr ? xt : xh;
            xv[it] = *reinterpret_cast<const float4*>(&xs[(base + r) * D + c4 * 4]);
        } else {
            xv[it] = (float4){0.f, 0.f, 0.f, 0.f};
        }
    }

    // ---- W fragments: 1 WH tile + 1 WT tile per wave (loads overlap X latency) ----
    f16x8 wf[2][4];               // [0]=WH tile w, [1]=WT tile w; x [ks]
#pragma unroll
    for (int ks = 0; ks < 4; ++ks) {
        const int k0 = ks * 32 + lq * 8;
        const float* p1 = WH + (w * 16 + lm) * D + k0;
        wf[0][ks] = cvt8(*reinterpret_cast<const float4*>(p1),
                         *reinterpret_cast<const float4*>(p1 + 4));
        const float* p2 = WT + (w * 16 + lm) * D + k0;
        wf[1][ks] = cvt8(*reinterpret_cast<const float4*>(p2),
                         *reinterpret_cast<const float4*>(p2 + 4));
    }

    // ---- convert + write staged X (loads already in flight/arrived) ----
#pragma unroll
    for (int it = 0; it < ITERS; ++it) {
        const int u = tid + it * 512;
        const int arr = (u >= PAD * 32);
        const int rem = arr ? (u - PAD * 32) : u;
        const int r = rem >> 5, c4 = rem & 31;
        _Float16* Xs = arr ? XT : XH;
        PK4 pk;
        pk.p[0] = __builtin_amdgcn_cvt_pkrtz(xv[it].x, xv[it].y);
        pk.p[1] = __builtin_amdgcn_cvt_pkrtz(xv[it].z, xv[it].w);
        *reinterpret_cast<ushort4*>(&Xs[r * 128 + ((c4 * 4) ^ ((r & 7) << 3))]) = pk.v;
    }
    __syncthreads();

    // ---- G_s = x_s @ [WA|WB]^T + [bA|bB]; wave owns col-tiles {w, 8+w}; fp16 -> LDS ----
#pragma unroll
    for (int side = 0; side < 2; ++side) {
        const _Float16* Xs = side ? XT : XH;
        const float* __restrict__ bA = side ? bT : bH;
        const float* __restrict__ bB = side ? bH : bT;
        _Float16* Gs = side ? GT : GH;

        f32x4 acc[TM][2];
#pragma unroll
        for (int ti = 0; ti < TM; ++ti)
#pragma unroll
            for (int c2 = 0; c2 < 2; ++c2) acc[ti][c2] = (f32x4){0.f, 0.f, 0.f, 0.f};

#pragma unroll
        for (int ks = 0; ks < 4; ++ks) {
            const int k0 = ks * 32 + lq * 8;
            const int kx = k0 ^ ((lm & 7) << 3);     // row = ti*16+lm -> row&7 == lm&7
            f16x8 q[TM];
#pragma unroll
            for (int ti = 0; ti < TM; ++ti)
                q[ti] = *reinterpret_cast<const f16x8*>(&Xs[(ti * 16 + lm) * 128 + kx]);
#pragma unroll
            for (int c2 = 0; c2 < 2; ++c2) {
                const int wfidx = side ? (c2 ^ 1) : c2;  // side t swaps WH/WT halves
#pragma unroll
                for (int ti = 0; ti < TM; ++ti)
                    acc[ti][c2] = __builtin_amdgcn_mfma_f32_16x16x32_f16(
                        wf[wfidx][ks], q[ti], acc[ti][c2], 0, 0, 0);
            }
        }

        // epilogue: lane holds G[i=ti*16+lm][n=ctl*16+lq*4+r], ctl = w or 8+w
#pragma unroll
        for (int c2 = 0; c2 < 2; ++c2) {
            const int ctl = c2 ? (8 + w) : w;
            const int nc = ctl * 16 + lq * 4;
            const float* bp = (ctl < 8) ? (bA + nc) : (bB + nc - 128);
            float4 b4 = *reinterpret_cast<const float4*>(bp);
#pragma unroll
            for (int ti = 0; ti < TM; ++ti) {
                int i = ti * 16 + lm;
                if (i < R) {
                    PK4 pk;
                    pk.p[0] = __builtin_amdgcn_cvt_pkrtz(acc[ti][c2][0] + b4.x,
                                                         acc[ti][c2][1] + b4.y);
                    pk.p[1] = __builtin_amdgcn_cvt_pkrtz(acc[ti][c2][2] + b4.z,
                                                         acc[ti][c2][3] + b4.w);
                    *reinterpret_cast<ushort4*>(&Gs[i * 256 + (nc ^ ((i & 7) << 3))]) = pk.v;
                }
            }
        }
    }
    __syncthreads();

    // ---- alpha = tanh(G_h @ G_t^T); wave w<TM owns i-tile w; no clamps (zero pad) ----
    float cs[3] = {0.f, 0.f, 0.f};
    if (w < TM) {
        f32x4 acc2[TM];
#pragma unroll
        for (int tj = 0; tj < TM; ++tj) acc2[tj] = (f32x4){0.f, 0.f, 0.f, 0.f};

        const int ri = w * 16 + lm;
#pragma unroll
        for (int ksa = 0; ksa < 8; ++ksa) {
            const int k0 = ksa * 32 + lq * 8;
            const int kx = k0 ^ ((lm & 7) << 3);
            f16x8 A = *reinterpret_cast<const f16x8*>(&GH[ri * 256 + kx]);
#pragma unroll
            for (int tj = 0; tj < TM; ++tj) {
                f16x8 B = *reinterpret_cast<const f16x8*>(&GT[(tj * 16 + lm) * 256 + kx]);
                acc2[tj] = __builtin_amdgcn_mfma_f32_16x16x32_f16(A, B, acc2[tj], 0, 0, 0);
            }
        }

        float at[TM][4];
#pragma unroll
        for (int tj = 0; tj < TM; ++tj)
#pragma unroll
            for (int r = 0; r < 4; ++r) at[tj][r] = tanh_fast(acc2[tj][r]);

        // row sums over j -> bh_s[i]
#pragma unroll
        for (int r = 0; r < 4; ++r) {
            float s = 0.f;
#pragma unroll
            for (int tj = 0; tj < TM; ++tj) s += at[tj][r];
            s += __shfl_xor(s, 1, 64);
            s += __shfl_xor(s, 2, 64);
            s += __shfl_xor(s, 4, 64);
            s += __shfl_xor(s, 8, 64);
            if (lm == 0) bh_s[w * 16 + lq * 4 + r] = s;
        }
        // col partial sums over this i-tile
#pragma unroll
        for (int tj = 0; tj < TM; ++tj) {
            float s = 0.f;
#pragma unroll
            for (int r = 0; r < 4; ++r) s += at[tj][r];
            s += __shfl_xor(s, 16, 64);
            s += __shfl_xor(s, 32, 64);
            cs[tj] = s;
        }
    }
    if (w < 3) {
#pragma unroll
        for (int tj = 0; tj < 3; ++tj)
            if (lq == 0) colpart[w * 48 + tj * 16 + lm] = (tj < TM) ? cs[tj] : 0.f;
    }
    __syncthreads();

    // ---- softmaxes: wave0 -> p_t (col means), wave1 -> p_h (row means) ----
    if (w == 0) {
        float v = (l < 48) ? (colpart[l] + colpart[48 + l] + colpart[96 + l]) : 0.f;
        float val = (l < R) ? v * invR : -INFINITY;
        float m = val;
        for (int o = 32; o; o >>= 1) m = fmaxf(m, __shfl_xor(m, o, 64));
        float e = (l < R) ? __expf(val - m) : 0.f;
        float s = e;
        for (int o = 32; o; o >>= 1) s += __shfl_xor(s, o, 64);
        if (l < R) pt_s[l] = __fdividef(e, s);
    } else if (w == 1) {
        float val = (l < R) ? bh_s[l] * invR : -INFINITY;
        float m = val;
        for (int o = 32; o; o >>= 1) m = fmaxf(m, __shfl_xor(m, o, 64));
        float e = (l < R) ? __expf(val - m) : 0.f;
        float s = e;
        for (int o = 32; o; o >>= 1) s += __shfl_xor(s, o, 64);
        if (l < R) ph_s[l] = __fdividef(e, s);
    }
    __syncthreads();

    // ---- outputs from LDS fp16 x copies (threads 0..255; rest idle) ----
    if (tid < 128) {
        const int c = tid;
        float a = 0.f;
        for (int j = 0; j < R; ++j)
            a += pt_s[j] * (float)XT[j * 128 + (c ^ ((j & 7) << 3))];
        ost[g * D + c] = a;
    } else if (tid < 256) {
        const int c = tid - 128;
        float a = 0.f;
        for (int i = 0; i < R; ++i)
            a += ph_s[i] * (float)XH[i * 128 + (c ^ ((i & 7) << 3))];
        osh[g * D + c] = a;
    }
}

__global__ __launch_bounds__(512, 2) void fused_kernel(
    const float* __restrict__ xnh, const float* __restrict__ xnt,
    const float* __restrict__ xlh, const float* __restrict__ xlt,
    const float* __restrict__ Wh, const float* __restrict__ bh,
    const float* __restrict__ Wt, const float* __restrict__ bt,
    const float* __restrict__ Whl, const float* __restrict__ bhl,
    const float* __restrict__ Wtl, const float* __restrict__ btl,
    float* __restrict__ out)
{
    __shared__ __align__(16) _Float16 GH[48 * 256];
    __shared__ __align__(16) _Float16 GT[48 * 256];
    __shared__ __align__(16) _Float16 XH[48 * 128];
    __shared__ __align__(16) _Float16 XT[48 * 128];
    __shared__ __align__(16) float colpart[144];
    __shared__ __align__(16) float bh_s[48];
    __shared__ __align__(16) float pt_s[48];
    __shared__ __align__(16) float ph_s[48];

    int idx = blockIdx.x;
    if (idx < 256)
        body<0>(idx, xnh, xnt, Wh, Wt, bh, bt, out + 0, out + 32768,
                GH, GT, XH, XT, colpart, bh_s, pt_s, ph_s);
    else
        body<1>(idx - 256, xlh, xlt, Whl, Wtl, bhl, btl, out + 65536, out + 98304,
                GH, GT, XH, XT, colpart, bh_s, pt_s, ph_s);
}

extern "C" void kernel_launch(void* const* d_in, const int* in_sizes, int n_in,
                              void* d_out, int out_size, void* d_ws, size_t ws_size,
                              hipStream_t stream) {
    const float* xnh   = (const float*)d_in[0];
    const float* xnt   = (const float*)d_in[1];
    const float* xlh   = (const float*)d_in[2];
    const float* xlt   = (const float*)d_in[3];
    const float* Wh_w  = (const float*)d_in[4];
    const float* Wh_b  = (const float*)d_in[5];
    const float* Wt_w  = (const float*)d_in[6];
    const float* Wt_b  = (const float*)d_in[7];
    const float* Whl_w = (const float*)d_in[8];
    const float* Whl_b = (const float*)d_in[9];
    const float* Wtl_w = (const float*)d_in[10];
    const float* Wtl_b = (const float*)d_in[11];

    float* out = (float*)d_out;

    fused_kernel<<<512, 512, 0, stream>>>(xnh, xnt, xlh, xlt,
                                          Wh_w, Wh_b, Wt_w, Wt_b,
                                          Whl_w, Whl_b, Wtl_w, Wtl_b, out);
}